// Round 2
// baseline (435.517 us; speedup 1.0000x reference)
//
#include <hip/hip_runtime.h>
#include <hip/hip_bf16.h>

// ---------------------------------------------------------------------------
// TensorProductLinearGate: fused CG tensor product + block linear + gate.
// N=65536 nodes, MUL=128.
//   s    = tp0 @ W0 /16 + b0            (tp0 = [x0*y0 ; dot(x1,y1)/sqrt3], K=256)
//   v1o  = (y1[i]*p0 + y0*p1[i]) /16    (p0 = x0@W1o_top, p1i = x1i@W1o_bot)
//   v1e  = (y1[i2]*q[i1]-y1[i1]*q[i2])/16   (q_i = x1i@W1e ; /sqrt2/sqrt128 = /16)
//   out  = [silu(s[256:]) | v1o*sig(s[0:128]) | v1e*sig(s[128:256])]
// bf16 MFMA 16x16x32, fp32 accum. Weights pre-transposed to [out][K] bf16 in ws.
// ---------------------------------------------------------------------------

typedef __bf16 bf16x8 __attribute__((ext_vector_type(8)));
typedef float f32x4 __attribute__((ext_vector_type(4)));
typedef unsigned short u16x8 __attribute__((ext_vector_type(8)));

#define W1OT_TOP 98304
#define W1OT_BOT 114688
#define W1ET     131072
#define INV16 0.0625f
#define INV_SQRT3 0.57735026918962576f

__device__ __forceinline__ unsigned short f2bf(float f) {
    unsigned u = __float_as_uint(f);
    u += 0x7FFFu + ((u >> 16) & 1u);
    return (unsigned short)(u >> 16);
}

// ---- weight prep: f32 [K][out] -> bf16 [out][K] (transposed), into ws ----
__global__ __launch_bounds__(256) void prep_w(const float* __restrict__ W0,
                                              const float* __restrict__ W1o,
                                              const float* __restrict__ W1e,
                                              unsigned short* __restrict__ ws) {
    int idx = blockIdx.x * 256 + threadIdx.x;   // grid covers exactly 147456
    float v;
    if (idx < 98304) {                 // W0T[o][k], o<384, k<256
        int o = idx >> 8, k = idx & 255;
        v = W0[k * 384 + o];
    } else if (idx < 114688) {         // W1o top half: k<128
        int j = idx - 98304; int o = j >> 7, k = j & 127;
        v = W1o[k * 128 + o];
    } else if (idx < 131072) {         // W1o bottom half: k in [128,256)
        int j = idx - 114688; int o = j >> 7, k = j & 127;
        v = W1o[(128 + k) * 128 + o];
    } else {                           // W1e
        int j = idx - 131072; int o = j >> 7, k = j & 127;
        v = W1e[k * 128 + o];
    }
    ws[idx] = f2bf(v);
}

// LDS layout (ushort units):
//   [0,2048)      x0sm   [16][128]
//   [2048,8192)   x1sm   [3][16][128]
//   [8192,12288)  tp0sm  [16][256]
// all rows XOR-swizzled by ((row&7)*8) on the 8-element-chunk index.
__global__ __launch_bounds__(256, 2) void tpl_gate(
    const float* __restrict__ x0, const float* __restrict__ x1,
    const float* __restrict__ y0, const float* __restrict__ y1,
    const float* __restrict__ b0, const unsigned short* __restrict__ ws,
    float* __restrict__ out) {
    __shared__ alignas(16) unsigned short sm[12288];
    __shared__ alignas(16) float ysm[64];      // [16 nodes][y0,y1x,y1y,y1z]
    __shared__ alignas(16) float b0sm[384];

    const int t = threadIdx.x;
    const int base = blockIdx.x * 16;

    // ----------------- staging: global f32 -> LDS bf16 -----------------
    {
        const int r = t >> 4, cg = t & 15, c0 = cg * 8;
        const int n = base + r;
        const int swz = (r & 7) * 8;
        const float w0v = y0[n];
        const float w1x = y1[n * 3 + 0], w1y = y1[n * 3 + 1], w1z = y1[n * 3 + 2];

        // x0 chunk + tp0 top (x0*y0)
        const float4* px = (const float4*)(x0 + (size_t)n * 128 + c0);
        float4 a4 = px[0], b4 = px[1];
        float xa[8] = {a4.x, a4.y, a4.z, a4.w, b4.x, b4.y, b4.z, b4.w};
        u16x8 q0, q1;
#pragma unroll
        for (int e = 0; e < 8; e++) { q0[e] = f2bf(xa[e]); q1[e] = f2bf(xa[e] * w0v); }
        *(u16x8*)(&sm[r * 128 + (c0 ^ swz)]) = q0;
        *(u16x8*)(&sm[8192 + r * 256 + (c0 ^ swz)]) = q1;

        // x1 chunk (3 components) + tp0 bottom (dot(x1,y1)/sqrt3)
        const float4* p1 = (const float4*)(x1 + (size_t)n * 384 + c0 * 3);
        float xb[24];
#pragma unroll
        for (int e = 0; e < 6; e++) {
            float4 v = p1[e];
            xb[e * 4 + 0] = v.x; xb[e * 4 + 1] = v.y; xb[e * 4 + 2] = v.z; xb[e * 4 + 3] = v.w;
        }
        u16x8 qx, qy, qz, qt;
#pragma unroll
        for (int e = 0; e < 8; e++) {
            float vx = xb[e * 3 + 0], vy = xb[e * 3 + 1], vz = xb[e * 3 + 2];
            qx[e] = f2bf(vx); qy[e] = f2bf(vy); qz[e] = f2bf(vz);
            qt[e] = f2bf((vx * w1x + vy * w1y + vz * w1z) * INV_SQRT3);
        }
        *(u16x8*)(&sm[2048 + r * 128 + (c0 ^ swz)]) = qx;
        *(u16x8*)(&sm[4096 + r * 128 + (c0 ^ swz)]) = qy;
        *(u16x8*)(&sm[6144 + r * 128 + (c0 ^ swz)]) = qz;
        *(u16x8*)(&sm[8192 + r * 256 + ((128 + c0) ^ swz)]) = qt;

        if (t < 16) {
            int nn = base + t;
            ysm[t * 4 + 0] = y0[nn];
            ysm[t * 4 + 1] = y1[nn * 3 + 0];
            ysm[t * 4 + 2] = y1[nn * 3 + 1];
            ysm[t * 4 + 3] = y1[nn * 3 + 2];
        }
        if (t < 96) ((float4*)b0sm)[t] = ((const float4*)b0)[t];
    }
    __syncthreads();

    // ----------------- MFMA phase -----------------
    const int wave = t >> 6, lane = t & 63;
    const int cl = lane & 15, g4 = lane >> 4;
    const int swzr = (cl & 7) * 8;
    const int o0A = wave * 16;        // o-tile pair: cols o0A.. and o0A+64..
    const int o0B = wave * 16 + 64;

    f32x4 accS[2][3], accP0[2], accP1[2][3], accQ[2][3];
#pragma unroll
    for (int p = 0; p < 2; p++) {
        accP0[p] = (f32x4)(0.0f);
#pragma unroll
        for (int g = 0; g < 3; g++) accS[p][g] = (f32x4)(0.0f);
#pragma unroll
        for (int i = 0; i < 3; i++) { accP1[p][i] = (f32x4)(0.0f); accQ[p][i] = (f32x4)(0.0f); }
    }
    const int oo[2] = {o0A, o0B};

    // s-path: tp0 (K=256) x W0T
#pragma unroll
    for (int ks = 0; ks < 8; ks++) {
        int eb = ks * 32 + g4 * 8;
        bf16x8 a = *(const bf16x8*)(&sm[8192 + cl * 256 + (eb ^ swzr)]);
#pragma unroll
        for (int p = 0; p < 2; p++) {
#pragma unroll
            for (int g = 0; g < 3; g++) {
                int row = g * 128 + oo[p] + cl;
                bf16x8 b = *(const bf16x8*)(&ws[row * 256 + eb]);
                accS[p][g] = __builtin_amdgcn_mfma_f32_16x16x32_bf16(a, b, accS[p][g], 0, 0, 0);
            }
        }
    }
    // v-path: x0/x1 (K=128) x {W1o_top, W1o_bot, W1e}
#pragma unroll
    for (int k = 0; k < 4; k++) {
        int eb = k * 32 + g4 * 8;
        bf16x8 a0 = *(const bf16x8*)(&sm[0    + cl * 128 + (eb ^ swzr)]);
        bf16x8 ax = *(const bf16x8*)(&sm[2048 + cl * 128 + (eb ^ swzr)]);
        bf16x8 ay = *(const bf16x8*)(&sm[4096 + cl * 128 + (eb ^ swzr)]);
        bf16x8 az = *(const bf16x8*)(&sm[6144 + cl * 128 + (eb ^ swzr)]);
#pragma unroll
        for (int p = 0; p < 2; p++) {
            int row = oo[p] + cl;
            bf16x8 bt = *(const bf16x8*)(&ws[W1OT_TOP + row * 128 + eb]);
            bf16x8 bb = *(const bf16x8*)(&ws[W1OT_BOT + row * 128 + eb]);
            bf16x8 be = *(const bf16x8*)(&ws[W1ET     + row * 128 + eb]);
            accP0[p]    = __builtin_amdgcn_mfma_f32_16x16x32_bf16(a0, bt, accP0[p], 0, 0, 0);
            accP1[p][0] = __builtin_amdgcn_mfma_f32_16x16x32_bf16(ax, bb, accP1[p][0], 0, 0, 0);
            accP1[p][1] = __builtin_amdgcn_mfma_f32_16x16x32_bf16(ay, bb, accP1[p][1], 0, 0, 0);
            accP1[p][2] = __builtin_amdgcn_mfma_f32_16x16x32_bf16(az, bb, accP1[p][2], 0, 0, 0);
            accQ[p][0]  = __builtin_amdgcn_mfma_f32_16x16x32_bf16(ax, be, accQ[p][0], 0, 0, 0);
            accQ[p][1]  = __builtin_amdgcn_mfma_f32_16x16x32_bf16(ay, be, accQ[p][1], 0, 0, 0);
            accQ[p][2]  = __builtin_amdgcn_mfma_f32_16x16x32_bf16(az, be, accQ[p][2], 0, 0, 0);
        }
    }

    // ----------------- epilogue: bias, gates, store -----------------
#pragma unroll
    for (int p = 0; p < 2; p++) {
        const int o = oo[p] + cl;         // 0..127 output channel
        const float b0a = b0sm[o];
        const float b0b = b0sm[128 + o];
        const float b0c = b0sm[256 + o];
#pragma unroll
        for (int j = 0; j < 4; j++) {
            const int r = g4 * 4 + j;
            float4 yv = ((const float4*)ysm)[r];
            const float yy0 = yv.x, y1x = yv.y, y1y = yv.z, y1z = yv.w;
            float s0 = accS[p][0][j] * INV16 + b0a;
            float s1 = accS[p][1][j] * INV16 + b0b;
            float s2 = accS[p][2][j] * INV16 + b0c;
            float g1o = INV16 / (1.0f + __expf(-s0));   // sigmoid * 1/16 folded
            float g1e = INV16 / (1.0f + __expf(-s1));
            float feat = s2 / (1.0f + __expf(-s2));     // silu
            float P0 = accP0[p][j];
            float v1o0 = (y1x * P0 + yy0 * accP1[p][0][j]) * g1o;
            float v1o1 = (y1y * P0 + yy0 * accP1[p][1][j]) * g1o;
            float v1o2 = (y1z * P0 + yy0 * accP1[p][2][j]) * g1o;
            float v1e0 = (y1z * accQ[p][1][j] - y1y * accQ[p][2][j]) * g1e;
            float v1e1 = (y1x * accQ[p][2][j] - y1z * accQ[p][0][j]) * g1e;
            float v1e2 = (y1y * accQ[p][0][j] - y1x * accQ[p][1][j]) * g1e;
            float* orow = out + (size_t)(base + r) * 896;
            orow[o] = feat;
            orow[128 + o * 3 + 0] = v1o0;
            orow[128 + o * 3 + 1] = v1o1;
            orow[128 + o * 3 + 2] = v1o2;
            orow[512 + o * 3 + 0] = v1e0;
            orow[512 + o * 3 + 1] = v1e1;
            orow[512 + o * 3 + 2] = v1e2;
        }
    }
}

extern "C" void kernel_launch(void* const* d_in, const int* in_sizes, int n_in,
                              void* d_out, int out_size, void* d_ws, size_t ws_size,
                              hipStream_t stream) {
    (void)in_sizes; (void)n_in; (void)out_size; (void)ws_size;
    const float* x0  = (const float*)d_in[0];
    const float* x1  = (const float*)d_in[1];
    const float* y0  = (const float*)d_in[2];
    const float* y1  = (const float*)d_in[3];
    const float* W0  = (const float*)d_in[4];
    const float* b0  = (const float*)d_in[5];
    const float* W1o = (const float*)d_in[6];
    const float* W1e = (const float*)d_in[7];
    unsigned short* ws = (unsigned short*)d_ws;
    float* out = (float*)d_out;

    prep_w<<<dim3(576), dim3(256), 0, stream>>>(W0, W1o, W1e, ws);
    tpl_gate<<<dim3(65536 / 16), dim3(256), 0, stream>>>(x0, x1, y0, y1, b0, ws, out);
}